// Round 8
// baseline (224.392 us; speedup 1.0000x reference)
//
#include <hip/hip_runtime.h>
#include <hip/hip_bf16.h>

#define T_TOK 4096
#define HD    1024
#define FFD   2048
#define NE    8

typedef __attribute__((ext_vector_type(8))) short short8;
typedef __attribute__((ext_vector_type(4))) float f32x4;

__device__ __forceinline__ unsigned short f2bf(float f) {
  __hip_bfloat16 h = __float2bfloat16(f);
  return __builtin_bit_cast(unsigned short, h);
}

__device__ __forceinline__ void gload_lds16(const unsigned short* g, unsigned short* l) {
  __builtin_amdgcn_global_load_lds(
      (const __attribute__((address_space(1))) unsigned int*)g,
      (__attribute__((address_space(3))) unsigned int*)l, 16, 0, 0);
}

// ---------------- gate: logits -> top2 (no atomics), x->bf16, zero out ----------------
__global__ __launch_bounds__(256) void gate_kernel(
    const float* __restrict__ x, const float* __restrict__ Wg,
    const float* __restrict__ bg,
    int* __restrict__ top_i, float2* __restrict__ top_w,
    unsigned short* __restrict__ xbf, float* __restrict__ out)
{
  {
    size_t b = ((size_t)blockIdx.x * 256 + threadIdx.x) * 16;
    float4 z = make_float4(0.f, 0.f, 0.f, 0.f);
#pragma unroll
    for (int q = 0; q < 4; ++q) *(float4*)(out + b + q * 4) = z;
  }

  const int wave = threadIdx.x >> 6;
  const int lane = threadIdx.x & 63;
  const int t = blockIdx.x * 4 + wave;
  if (t >= T_TOK) return;

  float acc[NE];
#pragma unroll
  for (int e = 0; e < NE; ++e) acc[e] = 0.f;

  const float* xr = x + (size_t)t * HD;
  unsigned short* xo = xbf + (size_t)t * HD;
#pragma unroll
  for (int it = 0; it < 4; ++it) {
    const int h0 = lane * 4 + it * 256;
    float4 xv = *(const float4*)(xr + h0);
#pragma unroll
    for (int j = 0; j < 4; ++j) {
      float xs = (&xv.x)[j];
      float4 a = *(const float4*)(Wg + (size_t)(h0 + j) * NE);
      float4 b = *(const float4*)(Wg + (size_t)(h0 + j) * NE + 4);
      acc[0] = fmaf(xs, a.x, acc[0]); acc[1] = fmaf(xs, a.y, acc[1]);
      acc[2] = fmaf(xs, a.z, acc[2]); acc[3] = fmaf(xs, a.w, acc[3]);
      acc[4] = fmaf(xs, b.x, acc[4]); acc[5] = fmaf(xs, b.y, acc[5]);
      acc[6] = fmaf(xs, b.z, acc[6]); acc[7] = fmaf(xs, b.w, acc[7]);
    }
    ushort4 u;
    u.x = f2bf(xv.x); u.y = f2bf(xv.y); u.z = f2bf(xv.z); u.w = f2bf(xv.w);
    *(ushort4*)(xo + h0) = u;
  }
#pragma unroll
  for (int off = 32; off > 0; off >>= 1) {
#pragma unroll
    for (int e = 0; e < NE; ++e) acc[e] += __shfl_xor(acc[e], off);
  }
  if (lane == 0) {
    float lg[NE];
#pragma unroll
    for (int e = 0; e < NE; ++e) lg[e] = acc[e] + bg[e];
    int i1 = 0;
#pragma unroll
    for (int e = 1; e < NE; ++e) if (lg[e] > lg[i1]) i1 = e;
    int i2 = (i1 == 0) ? 1 : 0;
#pragma unroll
    for (int e = 0; e < NE; ++e) if (e != i1 && lg[e] > lg[i2]) i2 = e;
    float p2 = expf(lg[i2] - lg[i1]);
    float s  = 1.f + p2;
    top_i[t] = i1 | (i2 << 8);
    top_w[t] = make_float2(1.f / s, p2 / s);
  }
}

// ---------------- route: per-expert compaction via prefix scan (deterministic) ----
__global__ __launch_bounds__(256) void route_kernel(
    const int* __restrict__ top_i, const float2* __restrict__ top_w,
    int* __restrict__ counts, int* __restrict__ ids, float* __restrict__ wts)
{
  const int e   = blockIdx.x;
  const int tid = threadIdx.x;
  __shared__ int psum[256];

  const int t0 = tid * 16;
  unsigned int flags = 0;
  int cnt = 0;
#pragma unroll
  for (int j = 0; j < 16; ++j) {
    int ti = top_i[t0 + j];
    bool m = ((ti & 255) == e) || (((ti >> 8) & 255) == e);
    flags |= (m ? 1u : 0u) << j;
    cnt += m;
  }
  psum[tid] = cnt;
  __syncthreads();
  for (int off = 1; off < 256; off <<= 1) {
    int v = (tid >= off) ? psum[tid - off] : 0;
    __syncthreads();
    psum[tid] += v;
    __syncthreads();
  }
  int rank = psum[tid] - cnt;
#pragma unroll
  for (int j = 0; j < 16; ++j) {
    if (flags & (1u << j)) {
      int t = t0 + j;
      int ti = top_i[t];
      float2 w = top_w[t];
      ids[e * T_TOK + rank] = t;
      wts[e * T_TOK + rank] = ((ti & 255) == e) ? w.x : w.y;
      ++rank;
    }
  }
  if (tid == 255) counts[e] = psum[255];
}

// ---------------- weight transpose + bf16 convert ----------------
__global__ __launch_bounds__(256) void transpose_cvt_kernel(
    const float* __restrict__ in, unsigned short* __restrict__ out,
    int R, int C)
{
  __shared__ float tile[64][69];
  const int z  = blockIdx.z;
  const int r0 = blockIdx.y * 64, c0 = blockIdx.x * 64;
  const int t  = threadIdx.x;
  const float* ip = in + ((size_t)z * R + r0) * C + c0;
  int tr = t >> 4, tc = (t & 15) * 4;
#pragma unroll
  for (int j = 0; j < 4; ++j) {
    float4 v = *(const float4*)(ip + (size_t)(tr + j * 16) * C + tc);
    float* tp = &tile[tr + j * 16][tc];
    tp[0] = v.x; tp[1] = v.y; tp[2] = v.z; tp[3] = v.w;
  }
  __syncthreads();
  unsigned short* op = out + ((size_t)z * C + c0) * R + r0;
  int oc = t >> 4, orr = (t & 15) * 4;
#pragma unroll
  for (int j = 0; j < 4; ++j) {
    int c = oc + j * 16;
    ushort4 w;
    w.x = f2bf(tile[orr + 0][c]);
    w.y = f2bf(tile[orr + 1][c]);
    w.z = f2bf(tile[orr + 2][c]);
    w.w = f2bf(tile[orr + 3][c]);
    *(ushort4*)(op + (size_t)c * R + orr) = w;
  }
}

// ---------------- grouped pair-GEMM: 2-phase stage-early dbuf, XCD-pinned ----------
// Grid: 1-D, e = bid&7 (XCD pin), slot = bid>>3; rt = slot % ntiles (fastest ->
// B-tile hot in the XCD's L2 while A panel streams+sticks), ct = slot / ntiles.
// Packed rows per expert padded to 256 (base stride).
// LDS XOR-swizzle verified (0 conflicts, r5-7). Loop = catalog T3 minimum 2-phase:
//   stage(t+1) -> ds_read+MFMA(t) -> vmcnt(0)+barrier   (one barrier, no drain stall)
template<int KD, int ND, int BM, int BN, int WM, int WN, bool G1M, bool GATHER_A>
__global__ __launch_bounds__(WM * WN * 64, 2) void pair_gemm_kernel(
    const unsigned short* __restrict__ A,
    const unsigned short* __restrict__ BT,
    const float* __restrict__ bias,
    const int* __restrict__ counts, const int* __restrict__ ids,
    const float* __restrict__ wts,
    unsigned short* __restrict__ Hout, float* __restrict__ out)
{
  constexpr int W   = WM * WN;
  constexpr int MF  = BM / WM / 16;
  constexpr int NF  = BN / WN / 16;
  constexpr int JA  = BM / (8 * W);
  constexpr int JB  = BN / (8 * W);
  constexpr int NT  = KD / 64;
  constexpr int CT  = ND / BN;
  constexpr int WMS = BM / WM;
  constexpr int WNS = BN / WN;

  const int e    = blockIdx.x & 7;
  const int slot = blockIdx.x >> 3;
  int cnt = 0, base = 0;
#pragma unroll
  for (int k = 0; k < NE; ++k) {
    int c = counts[k];
    if (k < e)  base += (c + 255) & ~255;
    if (k == e) cnt = c;
  }
  const int ntiles = (cnt + BM - 1) / BM;
  if (slot >= ntiles * CT) return;
  const int rt   = slot % ntiles;
  const int ct   = slot / ntiles;
  const int row0 = base + rt * BM;

  __shared__ __align__(16) unsigned short As[2][BM * 64];
  __shared__ __align__(16) unsigned short Bs[2][BN * 64];

  const int tid  = threadIdx.x;
  const int w    = tid >> 6;
  const int lane = tid & 63;
  const int g    = lane >> 4;
  const int rA   = lane & 15;
  const int wr   = w / WN;
  const int wc   = w % WN;
  const int sw   = rA & 7;
  const int srow = lane >> 3;
  const int lc8  = ((lane & 7) ^ srow) * 8;

  const unsigned short* aptr[JA];
#pragma unroll
  for (int jj = 0; jj < JA; ++jj) {
    const int lrow = (w * JA + jj) * 8 + srow;
    int src;
    if constexpr (GATHER_A) {
      int i = rt * BM + lrow;
      src = ids[e * T_TOK + (i < cnt ? i : cnt - 1)];
    } else {
      src = row0 + lrow;
    }
    aptr[jj] = A + (size_t)src * KD + lc8;
  }
  const unsigned short* bptr[JB];
#pragma unroll
  for (int jj = 0; jj < JB; ++jj) {
    const int lrow = (w * JB + jj) * 8 + srow;
    bptr[jj] = BT + ((size_t)e * ND + ct * BN + lrow) * KD + lc8;
  }

  f32x4 acc[MF][NF];
#pragma unroll
  for (int mf = 0; mf < MF; ++mf)
#pragma unroll
    for (int nf = 0; nf < NF; ++nf)
      acc[mf][nf] = (f32x4){0.f, 0.f, 0.f, 0.f};

  auto stage = [&](int buf, int kc) {
#pragma unroll
    for (int jj = 0; jj < JA; ++jj)
      gload_lds16(aptr[jj] + kc, &As[buf][(w * JA + jj) * 8 * 64]);
#pragma unroll
    for (int jj = 0; jj < JB; ++jj)
      gload_lds16(bptr[jj] + kc, &Bs[buf][(w * JB + jj) * 8 * 64]);
  };

  stage(0, 0);
  __syncthreads();   // drain tile-0 loads + barrier

#pragma unroll 2
  for (int t = 0; t < NT; ++t) {
    const int cur = t & 1;
    if (t + 1 < NT) stage(cur ^ 1, (t + 1) * 64);   // in flight across compute
    __builtin_amdgcn_sched_barrier(0);
#pragma unroll
    for (int ks = 0; ks < 2; ++ks) {
      const int pc = ((ks * 4 + g) ^ sw) << 3;
      short8 bf[NF];
#pragma unroll
      for (int nf = 0; nf < NF; ++nf)
        bf[nf] = *(const short8*)&Bs[cur][(wc * WNS + nf * 16 + rA) * 64 + pc];
#pragma unroll
      for (int mf = 0; mf < MF; ++mf) {
        short8 af = *(const short8*)&As[cur][(wr * WMS + mf * 16 + rA) * 64 + pc];
#pragma unroll
        for (int nf = 0; nf < NF; ++nf)
          acc[mf][nf] = __builtin_amdgcn_mfma_f32_16x16x32_bf16(
              af, bf[nf], acc[mf][nf], 0, 0, 0);
      }
    }
    asm volatile("s_waitcnt vmcnt(0)" ::: "memory");   // t+1 loads (covered by MFMA)
    __builtin_amdgcn_sched_barrier(0);
    __builtin_amdgcn_s_barrier();
    __builtin_amdgcn_sched_barrier(0);
  }

  // ---- epilogue ----
  float bv[NF];
#pragma unroll
  for (int nf = 0; nf < NF; ++nf)
    bv[nf] = bias[e * ND + ct * BN + wc * WNS + nf * 16 + rA];

  if constexpr (G1M) {
#pragma unroll
    for (int mf = 0; mf < MF; ++mf)
#pragma unroll
      for (int r = 0; r < 4; ++r) {
        const int row = row0 + wr * WMS + mf * 16 + g * 4 + r;
        unsigned short* hrow = Hout + (size_t)row * FFD + ct * BN + wc * WNS + rA;
#pragma unroll
        for (int nf = 0; nf < NF; ++nf)
          hrow[nf * 16] = f2bf(fmaxf(acc[mf][nf][r] + bv[nf], 0.f));
      }
  } else {
#pragma unroll
    for (int mf = 0; mf < MF; ++mf)
#pragma unroll
      for (int r = 0; r < 4; ++r) {
        const int i = rt * BM + wr * WMS + mf * 16 + g * 4 + r;
        if (i >= cnt) continue;
        const int tok = ids[e * T_TOK + i];
        const float wt = wts[e * T_TOK + i];
        float* orow = out + (size_t)tok * HD + ct * BN + wc * WNS + rA;
#pragma unroll
        for (int nf = 0; nf < NF; ++nf)
          atomicAdd(&orow[nf * 16], wt * (acc[mf][nf][r] + bv[nf]));
      }
  }
}

extern "C" void kernel_launch(void* const* d_in, const int* in_sizes, int n_in,
                              void* d_out, int out_size, void* d_ws, size_t ws_size,
                              hipStream_t stream) {
  const float* x  = (const float*)d_in[0];
  const float* Wg = (const float*)d_in[1];
  const float* bg = (const float*)d_in[2];
  const float* W1 = (const float*)d_in[3];
  const float* b1 = (const float*)d_in[4];
  const float* W2 = (const float*)d_in[5];
  const float* b2 = (const float*)d_in[6];
  float* out = (float*)d_out;

  // ws: [counts 512B][top_i 16K][top_w 32K][ids 128K][wts 128K]
  //     [xbf 8MB][WT 32MB (W1T then W2T)][H 40MB (10240 rows, 256-padded packing)]
  const size_t OFF_TOPI = 512;
  const size_t OFF_TOPW = OFF_TOPI + (size_t)T_TOK * 4;
  const size_t OFF_IDS  = OFF_TOPW + (size_t)T_TOK * 8;
  const size_t OFF_WTS  = OFF_IDS + (size_t)T_TOK * NE * 4;
  const size_t OFF_XBF  = OFF_WTS + (size_t)T_TOK * NE * 4;
  const size_t OFF_WT   = OFF_XBF + (size_t)T_TOK * HD * 2;
  const size_t OFF_H    = OFF_WT + (size_t)NE * HD * FFD * 2;
  const size_t REQ      = OFF_H + (size_t)10240 * FFD * 2;   // ~80.6 MB

  if (ws_size < REQ) return;

  int*            counts = (int*)d_ws;
  int*            top_i  = (int*)((char*)d_ws + OFF_TOPI);
  float2*         top_w  = (float2*)((char*)d_ws + OFF_TOPW);
  int*            ids    = (int*)((char*)d_ws + OFF_IDS);
  float*          wts    = (float*)((char*)d_ws + OFF_WTS);
  unsigned short* xbf    = (unsigned short*)((char*)d_ws + OFF_XBF);
  unsigned short* WT     = (unsigned short*)((char*)d_ws + OFF_WT);
  unsigned short* H      = (unsigned short*)((char*)d_ws + OFF_H);

  gate_kernel<<<T_TOK / 4, 256, 0, stream>>>(x, Wg, bg, top_i, top_w, xbf, out);
  route_kernel<<<NE, 256, 0, stream>>>(top_i, top_w, counts, ids, wts);

  transpose_cvt_kernel<<<dim3(FFD / 64, HD / 64, NE), 256, 0, stream>>>(W1, WT, HD, FFD);
  // G1: 256x256 tile, 8 waves, 128KB LDS dbuf; slots = 16 max tiles * 8 ct = 128
  pair_gemm_kernel<HD, FFD, 256, 256, 2, 4, true, true>
      <<<NE * 128, 512, 0, stream>>>(xbf, WT, b1, counts, ids, wts, H, nullptr);

  // W1T dead; reuse buffer for W2T
  transpose_cvt_kernel<<<dim3(HD / 64, FFD / 64, NE), 256, 0, stream>>>(W2, WT, FFD, HD);
  // G2: 128x128 tile, 4 waves, 64KB LDS dbuf (2 blk/CU); slots = 32 * 8 = 256
  pair_gemm_kernel<FFD, HD, 128, 128, 2, 2, false, false>
      <<<NE * 256, 256, 0, stream>>>(H, WT, b2, counts, ids, wts, nullptr, out);
}

// Round 9
// 175.161 us; speedup vs baseline: 1.2811x; 1.2811x over previous
//
#include <hip/hip_runtime.h>
#include <hip/hip_bf16.h>

#define T_TOK 4096
#define HD    1024
#define FFD   2048
#define NE    8

typedef __attribute__((ext_vector_type(8))) short short8;
typedef __attribute__((ext_vector_type(4))) float f32x4;

__device__ __forceinline__ unsigned short f2bf(float f) {
  __hip_bfloat16 h = __float2bfloat16(f);
  return __builtin_bit_cast(unsigned short, h);
}

__device__ __forceinline__ void gload_lds16(const unsigned short* g, unsigned short* l) {
  __builtin_amdgcn_global_load_lds(
      (const __attribute__((address_space(1))) unsigned int*)g,
      (__attribute__((address_space(3))) unsigned int*)l, 16, 0, 0);
}

// ---------------- gate: logits -> top2 (no atomics), x->bf16, zero out ----------------
__global__ __launch_bounds__(256) void gate_kernel(
    const float* __restrict__ x, const float* __restrict__ Wg,
    const float* __restrict__ bg,
    int* __restrict__ top_i, float2* __restrict__ top_w,
    unsigned short* __restrict__ xbf, float* __restrict__ out)
{
  {
    size_t b = ((size_t)blockIdx.x * 256 + threadIdx.x) * 16;
    float4 z = make_float4(0.f, 0.f, 0.f, 0.f);
#pragma unroll
    for (int q = 0; q < 4; ++q) *(float4*)(out + b + q * 4) = z;
  }

  const int wave = threadIdx.x >> 6;
  const int lane = threadIdx.x & 63;
  const int t = blockIdx.x * 4 + wave;
  if (t >= T_TOK) return;

  float acc[NE];
#pragma unroll
  for (int e = 0; e < NE; ++e) acc[e] = 0.f;

  const float* xr = x + (size_t)t * HD;
  unsigned short* xo = xbf + (size_t)t * HD;
#pragma unroll
  for (int it = 0; it < 4; ++it) {
    const int h0 = lane * 4 + it * 256;
    float4 xv = *(const float4*)(xr + h0);
#pragma unroll
    for (int j = 0; j < 4; ++j) {
      float xs = (&xv.x)[j];
      float4 a = *(const float4*)(Wg + (size_t)(h0 + j) * NE);
      float4 b = *(const float4*)(Wg + (size_t)(h0 + j) * NE + 4);
      acc[0] = fmaf(xs, a.x, acc[0]); acc[1] = fmaf(xs, a.y, acc[1]);
      acc[2] = fmaf(xs, a.z, acc[2]); acc[3] = fmaf(xs, a.w, acc[3]);
      acc[4] = fmaf(xs, b.x, acc[4]); acc[5] = fmaf(xs, b.y, acc[5]);
      acc[6] = fmaf(xs, b.z, acc[6]); acc[7] = fmaf(xs, b.w, acc[7]);
    }
    ushort4 u;
    u.x = f2bf(xv.x); u.y = f2bf(xv.y); u.z = f2bf(xv.z); u.w = f2bf(xv.w);
    *(ushort4*)(xo + h0) = u;
  }
#pragma unroll
  for (int off = 32; off > 0; off >>= 1) {
#pragma unroll
    for (int e = 0; e < NE; ++e) acc[e] += __shfl_xor(acc[e], off);
  }
  if (lane == 0) {
    float lg[NE];
#pragma unroll
    for (int e = 0; e < NE; ++e) lg[e] = acc[e] + bg[e];
    int i1 = 0;
#pragma unroll
    for (int e = 1; e < NE; ++e) if (lg[e] > lg[i1]) i1 = e;
    int i2 = (i1 == 0) ? 1 : 0;
#pragma unroll
    for (int e = 0; e < NE; ++e) if (e != i1 && lg[e] > lg[i2]) i2 = e;
    float p2 = expf(lg[i2] - lg[i1]);
    float s  = 1.f + p2;
    top_i[t] = i1 | (i2 << 8);
    top_w[t] = make_float2(1.f / s, p2 / s);
  }
}

// ---------------- route: per-expert compaction via prefix scan (deterministic) ----
__global__ __launch_bounds__(256) void route_kernel(
    const int* __restrict__ top_i, const float2* __restrict__ top_w,
    int* __restrict__ counts, int* __restrict__ ids, float* __restrict__ wts)
{
  const int e   = blockIdx.x;
  const int tid = threadIdx.x;
  __shared__ int psum[256];

  const int t0 = tid * 16;
  unsigned int flags = 0;
  int cnt = 0;
#pragma unroll
  for (int j = 0; j < 16; ++j) {
    int ti = top_i[t0 + j];
    bool m = ((ti & 255) == e) || (((ti >> 8) & 255) == e);
    flags |= (m ? 1u : 0u) << j;
    cnt += m;
  }
  psum[tid] = cnt;
  __syncthreads();
  for (int off = 1; off < 256; off <<= 1) {
    int v = (tid >= off) ? psum[tid - off] : 0;
    __syncthreads();
    psum[tid] += v;
    __syncthreads();
  }
  int rank = psum[tid] - cnt;
#pragma unroll
  for (int j = 0; j < 16; ++j) {
    if (flags & (1u << j)) {
      int t = t0 + j;
      int ti = top_i[t];
      float2 w = top_w[t];
      ids[e * T_TOK + rank] = t;
      wts[e * T_TOK + rank] = ((ti & 255) == e) ? w.x : w.y;
      ++rank;
    }
  }
  if (tid == 255) counts[e] = psum[255];
}

// ---------------- weight transpose + bf16 convert ----------------
__global__ __launch_bounds__(256) void transpose_cvt_kernel(
    const float* __restrict__ in, unsigned short* __restrict__ out,
    int R, int C)
{
  __shared__ float tile[64][69];
  const int z  = blockIdx.z;
  const int r0 = blockIdx.y * 64, c0 = blockIdx.x * 64;
  const int t  = threadIdx.x;
  const float* ip = in + ((size_t)z * R + r0) * C + c0;
  int tr = t >> 4, tc = (t & 15) * 4;
#pragma unroll
  for (int j = 0; j < 4; ++j) {
    float4 v = *(const float4*)(ip + (size_t)(tr + j * 16) * C + tc);
    float* tp = &tile[tr + j * 16][tc];
    tp[0] = v.x; tp[1] = v.y; tp[2] = v.z; tp[3] = v.w;
  }
  __syncthreads();
  unsigned short* op = out + ((size_t)z * C + c0) * R + r0;
  int oc = t >> 4, orr = (t & 15) * 4;
#pragma unroll
  for (int j = 0; j < 4; ++j) {
    int c = oc + j * 16;
    ushort4 w;
    w.x = f2bf(tile[orr + 0][c]);
    w.y = f2bf(tile[orr + 1][c]);
    w.z = f2bf(tile[orr + 2][c]);
    w.w = f2bf(tile[orr + 3][c]);
    *(ushort4*)(op + (size_t)c * R + orr) = w;
  }
}

// ---------------- grouped pair-GEMM: m97 structure + XCD pinning -----------------
// 128^2 tile, 4 waves, single-buffered 32KB LDS, 2 barriers/K-step, 4 blk/CU.
// e = bid&7 pins each expert to one XCD; rt fastest -> per-XCD working set
// (A panel ~2MB + B tile 0.25MB) is L2-resident. XOR swizzle: 0 conflicts (r5-8).
// G1M: Hout = relu(A@B^T + b1); else out[tok] += wt*(A@B^T + b2) (atomic).
template<int KD, int ND, bool G1M, bool GATHER_A>
__global__ __launch_bounds__(256, 4) void pair_gemm128_kernel(
    const unsigned short* __restrict__ A,
    const unsigned short* __restrict__ BT,
    const float* __restrict__ bias,
    const int* __restrict__ counts, const int* __restrict__ ids,
    const float* __restrict__ wts,
    unsigned short* __restrict__ Hout, float* __restrict__ out)
{
  constexpr int CT = ND / 128;

  const int e    = blockIdx.x & 7;
  const int slot = blockIdx.x >> 3;
  int cnt = 0, base = 0;
#pragma unroll
  for (int k = 0; k < NE; ++k) {
    int c = counts[k];
    if (k < e)  base += (c + 255) & ~255;
    if (k == e) cnt = c;
  }
  const int ntiles = (cnt + 127) >> 7;
  if (slot >= ntiles * CT) return;
  const int rt   = slot % ntiles;   // fastest -> B tile hot in this XCD's L2
  const int ct   = slot / ntiles;
  const int row0 = base + rt * 128;

  __shared__ __align__(16) unsigned short As[128 * 64];
  __shared__ __align__(16) unsigned short Bs[128 * 64];

  const int tid  = threadIdx.x;
  const int w    = tid >> 6;
  const int lane = tid & 63;
  const int g    = lane >> 4;     // k-group 0..3
  const int rA   = lane & 15;     // row/col within fragment
  const int wr   = w >> 1;        // wave quadrant row 0..1
  const int wc   = w & 1;         // wave quadrant col 0..1
  const int sw   = rA & 7;        // read-side swizzle key
  const int srow = lane >> 3;                 // staging row in 8-row group
  const int lc8  = ((lane & 7) ^ srow) * 8;   // pre-swizzled source chunk

  // per-thread A-row source pointers (ids indirection for G1)
  const unsigned short* arow[4];
#pragma unroll
  for (int jj = 0; jj < 4; ++jj) {
    const int lrow = w * 32 + jj * 8 + srow;
    int src;
    if constexpr (GATHER_A) {
      int i = rt * 128 + lrow;
      src = ids[e * T_TOK + (i < cnt ? i : cnt - 1)];
    } else {
      src = row0 + lrow;
    }
    arow[jj] = A + (size_t)src * KD + lc8;
  }
  const unsigned short* Bb = BT + ((size_t)e * ND + (size_t)ct * 128) * KD + lc8;

  f32x4 acc[4][4];
#pragma unroll
  for (int mf = 0; mf < 4; ++mf)
#pragma unroll
    for (int nf = 0; nf < 4; ++nf)
      acc[mf][nf] = (f32x4){0.f, 0.f, 0.f, 0.f};

  for (int kc = 0; kc < KD; kc += 64) {
    __syncthreads();   // all waves done reading As/Bs
#pragma unroll
    for (int jj = 0; jj < 4; ++jj) {
      const int rg = w * 32 + jj * 8;
      gload_lds16(arow[jj] + kc, &As[rg * 64]);
      gload_lds16(Bb + (size_t)(rg + srow) * KD + kc, &Bs[rg * 64]);
    }
    __syncthreads();   // drain; 4 blk/CU of cross-block TLP hides it (m97 mechanism)
#pragma unroll
    for (int ks = 0; ks < 2; ++ks) {
      const int pc = ((ks * 4 + g) ^ sw) << 3;
      short8 af[4], bf[4];
#pragma unroll
      for (int mf = 0; mf < 4; ++mf)
        af[mf] = *(const short8*)&As[(wr * 64 + mf * 16 + rA) * 64 + pc];
#pragma unroll
      for (int nf = 0; nf < 4; ++nf)
        bf[nf] = *(const short8*)&Bs[(wc * 64 + nf * 16 + rA) * 64 + pc];
#pragma unroll
      for (int mf = 0; mf < 4; ++mf)
#pragma unroll
        for (int nf = 0; nf < 4; ++nf)
          acc[mf][nf] = __builtin_amdgcn_mfma_f32_16x16x32_bf16(
              af[mf], bf[nf], acc[mf][nf], 0, 0, 0);
    }
  }

  // ---- epilogue ----
  float bv[4];
#pragma unroll
  for (int nf = 0; nf < 4; ++nf)
    bv[nf] = bias[e * ND + ct * 128 + wc * 64 + nf * 16 + rA];

  if constexpr (G1M) {
#pragma unroll
    for (int mf = 0; mf < 4; ++mf)
#pragma unroll
      for (int r = 0; r < 4; ++r) {
        const int row = row0 + wr * 64 + mf * 16 + g * 4 + r;
        unsigned short* hrow = Hout + (size_t)row * FFD + ct * 128 + wc * 64 + rA;
#pragma unroll
        for (int nf = 0; nf < 4; ++nf)
          hrow[nf * 16] = f2bf(fmaxf(acc[mf][nf][r] + bv[nf], 0.f));
      }
  } else {
#pragma unroll
    for (int mf = 0; mf < 4; ++mf)
#pragma unroll
      for (int r = 0; r < 4; ++r) {
        const int i = rt * 128 + wr * 64 + mf * 16 + g * 4 + r;
        if (i >= cnt) continue;
        const int tok = ids[e * T_TOK + i];
        const float wt = wts[e * T_TOK + i];
        float* orow = out + (size_t)tok * HD + ct * 128 + wc * 64 + rA;
#pragma unroll
        for (int nf = 0; nf < 4; ++nf)
          atomicAdd(&orow[nf * 16], wt * (acc[mf][nf][r] + bv[nf]));
      }
  }
}

extern "C" void kernel_launch(void* const* d_in, const int* in_sizes, int n_in,
                              void* d_out, int out_size, void* d_ws, size_t ws_size,
                              hipStream_t stream) {
  const float* x  = (const float*)d_in[0];
  const float* Wg = (const float*)d_in[1];
  const float* bg = (const float*)d_in[2];
  const float* W1 = (const float*)d_in[3];
  const float* b1 = (const float*)d_in[4];
  const float* W2 = (const float*)d_in[5];
  const float* b2 = (const float*)d_in[6];
  float* out = (float*)d_out;

  // ws: [counts 512B][top_i 16K][top_w 32K][ids 128K][wts 128K]
  //     [xbf 8MB][WT 32MB (W1T then W2T)][H 40MB (10240 rows, 256-padded packing)]
  const size_t OFF_TOPI = 512;
  const size_t OFF_TOPW = OFF_TOPI + (size_t)T_TOK * 4;
  const size_t OFF_IDS  = OFF_TOPW + (size_t)T_TOK * 8;
  const size_t OFF_WTS  = OFF_IDS + (size_t)T_TOK * NE * 4;
  const size_t OFF_XBF  = OFF_WTS + (size_t)T_TOK * NE * 4;
  const size_t OFF_WT   = OFF_XBF + (size_t)T_TOK * HD * 2;
  const size_t OFF_H    = OFF_WT + (size_t)NE * HD * FFD * 2;
  const size_t REQ      = OFF_H + (size_t)10240 * FFD * 2;   // ~80.6 MB

  if (ws_size < REQ) return;

  int*            counts = (int*)d_ws;
  int*            top_i  = (int*)((char*)d_ws + OFF_TOPI);
  float2*         top_w  = (float2*)((char*)d_ws + OFF_TOPW);
  int*            ids    = (int*)((char*)d_ws + OFF_IDS);
  float*          wts    = (float*)((char*)d_ws + OFF_WTS);
  unsigned short* xbf    = (unsigned short*)((char*)d_ws + OFF_XBF);
  unsigned short* WT     = (unsigned short*)((char*)d_ws + OFF_WT);
  unsigned short* H      = (unsigned short*)((char*)d_ws + OFF_H);

  gate_kernel<<<T_TOK / 4, 256, 0, stream>>>(x, Wg, bg, top_i, top_w, xbf, out);
  route_kernel<<<NE, 256, 0, stream>>>(top_i, top_w, counts, ids, wts);

  transpose_cvt_kernel<<<dim3(FFD / 64, HD / 64, NE), 256, 0, stream>>>(W1, WT, HD, FFD);
  // G1: worst case ntiles=32, CT=16 -> 512 slots/expert (extras early-exit)
  pair_gemm128_kernel<HD, FFD, true, true>
      <<<NE * 512, 256, 0, stream>>>(xbf, WT, b1, counts, ids, wts, H, nullptr);

  // W1T dead; reuse buffer for W2T
  transpose_cvt_kernel<<<dim3(HD / 64, FFD / 64, NE), 256, 0, stream>>>(W2, WT, FFD, HD);
  // G2: worst case ntiles=32, CT=8 -> 256 slots/expert
  pair_gemm128_kernel<FFD, HD, false, false>
      <<<NE * 256, 256, 0, stream>>>(H, WT, b2, counts, ids, wts, nullptr, out);
}